// Round 3
// baseline (996.737 us; speedup 1.0000x reference)
//
#include <hip/hip_runtime.h>

#define D_ 768
#define B_ 2048
#define NDOM 9
#define NTOT 10
#define MT 128
#define NT 128
#define KT 32
#define LDK 40     // padded LDS leading dim (fp16): 80B row stride, 16B-aligned
#define NTILES 6   // 768 / 128
#define KI1 (D_ / KT)   // 24

typedef _Float16 f16;
typedef _Float16 f16x8 __attribute__((ext_vector_type(8)));
typedef _Float16 f16x4 __attribute__((ext_vector_type(4)));
typedef _Float16 f16x2 __attribute__((ext_vector_type(2)));
typedef float f32x4 __attribute__((ext_vector_type(4)));

static __device__ __forceinline__ f16x2 pkrtz(float a, float b) {
  return __builtin_bit_cast(f16x2, __builtin_amdgcn_cvt_pkrtz(a, b));
}

// ---------------------------------------------------------------- bucket ----
__global__ __launch_bounds__(256) void bucket_kernel(const int* cat32, int* perm,
                                                     int* off, int* cnt, int* dom) {
  __shared__ int scnt[NDOM], soff[NDOM], scur[NDOM];
  __shared__ int odd_nz;
  int t = threadIdx.x;
  if (t == 0) odd_nz = 0;
  if (t < NDOM) scnt[t] = 0;
  __syncthreads();
  int loc = 0;
  for (int i = t; i < B_; i += 256)
    if ((i & 1) && cat32[i] != 0) loc = 1;
  if (loc) atomicOr(&odd_nz, 1);
  __syncthreads();
  int strd = odd_nz ? 1 : 2;
  for (int i = t; i < B_; i += 256) atomicAdd(&scnt[cat32[i * strd]], 1);
  __syncthreads();
  if (t == 0) { int a = 0; for (int n = 0; n < NDOM; n++) { soff[n] = a; a += scnt[n]; } }
  __syncthreads();
  if (t < NDOM) { scur[t] = soff[t]; off[t] = soff[t]; cnt[t] = scnt[t]; }
  __syncthreads();
  for (int i = t; i < B_; i += 256) {
    int n = cat32[i * strd];
    int pos = atomicAdd(&scur[n], 1);
    perm[pos] = i;
    dom[pos] = n;
  }
}

// ---------------------------------------------------------------- layer 1 ---
struct L1P {
  const float* x[2];
  const float* W1[2]; const float* b1[2];
  const float* sW1[2]; const float* sb1[2];
  const float* gW1[2]; const float* gb1[2];
  const float* demb;
  const int* perm; const int* off; const int* cnt;
  f16* h;
};

__global__ __launch_bounds__(256, 3) void layer1_kernel(L1P p) {
  const int z = blockIdx.z;
  const int g = blockIdx.y;
  const int mt = blockIdx.x / NTILES;
  const int nt = blockIdx.x % NTILES;

  int row_off, row_cnt, slot, gdom = 0;
  const float* Wp; const float* bias;
  bool isGate = false;
  if (g < 54) {
    int n = g / 6, e = g % 6;
    row_off = p.off[n]; row_cnt = p.cnt[n];
    Wp = p.W1[z] + (size_t)(n * 6 + e) * D_ * D_;
    bias = p.b1[z] + (n * 6 + e) * D_;
    slot = e;
  } else if (g < 58) {
    int e = g - 54;
    row_off = 0; row_cnt = B_;
    Wp = p.sW1[z] + (size_t)e * D_ * D_;
    bias = p.sb1[z] + e * D_;
    slot = 6 + e;
  } else {
    int n = g - 58;
    row_off = p.off[n]; row_cnt = p.cnt[n];
    Wp = p.gW1[z] + (size_t)n * 2 * D_ * D_;
    bias = p.gb1[z] + n * D_;
    slot = 10; isGate = true; gdom = n;
  }
  if (mt * MT >= row_cnt) return;

  __shared__ f16 As[2][MT][LDK];
  __shared__ f16 Bs[2][NT][LDK];

  const int t = threadIdx.x;
  const int wave = t >> 6, lane = t & 63;
  const int wr = (wave >> 1) * 64, wc = (wave & 1) * 64;
  const int r0 = lane & 15, q = lane >> 4;
  const int jbase = nt * NT;

  const int ar = t >> 1, akq = (t & 1) * 16;
  const int bj = (t >> 3) * 4, bk = (t & 7) * 4;

  const bool rowok = (mt * MT + ar) < row_cnt;
  const float* arow = p.x[z] + (size_t)(rowok ? p.perm[row_off + mt * MT + ar] : 0) * D_;
  const float* dembn = p.demb + (size_t)gdom * D_;

  const int kiters = isGate ? 2 * KI1 : KI1;

  f32x4 av[4], wv[4];

  auto LOAD = [&](int kk) {
    const int k0 = kk * KT;
    const float* ap = arow; int ac = k0;
    if (isGate) { if (k0 < D_) { ap = dembn; } else { ac = k0 - D_; } }
#pragma unroll
    for (int i = 0; i < 4; i++) av[i] = *(const f32x4*)(ap + ac + akq + i * 4);
#pragma unroll
    for (int i = 0; i < 4; i++) wv[i] = *(const f32x4*)(Wp + (size_t)(k0 + bk + i) * D_ + jbase + bj);
  };
  auto CVTSTORE = [&](int buf) {
    union { f16x8 v8[2]; f16x2 p2[8]; } ua;
#pragma unroll
    for (int i = 0; i < 4; i++) {
      ua.p2[2 * i]     = pkrtz(av[i][0], av[i][1]);
      ua.p2[2 * i + 1] = pkrtz(av[i][2], av[i][3]);
    }
    *(f16x8*)&As[buf][ar][akq]     = ua.v8[0];
    *(f16x8*)&As[buf][ar][akq + 8] = ua.v8[1];
#pragma unroll
    for (int j = 0; j < 4; j++) {
      union { f16x4 v; f16x2 p2[2]; } ub;
      ub.p2[0] = pkrtz(wv[0][j], wv[1][j]);
      ub.p2[1] = pkrtz(wv[2][j], wv[3][j]);
      *(f16x4*)&Bs[buf][bj + j][bk] = ub.v;
    }
  };

  f32x4 acc[4][4];
#pragma unroll
  for (int a = 0; a < 4; a++)
#pragma unroll
    for (int b = 0; b < 4; b++) acc[a][b] = (f32x4){0.f, 0.f, 0.f, 0.f};

  LOAD(0);
  CVTSTORE(0);
  __syncthreads();

  for (int kk = 0; kk < kiters; kk++) {
    const int cur = kk & 1;
    if (kk + 1 < kiters) LOAD(kk + 1);
    f16x8 af[4], bf[4];
#pragma unroll
    for (int m = 0; m < 4; m++) af[m] = *(const f16x8*)&As[cur][wr + m * 16 + r0][q * 8];
#pragma unroll
    for (int nn = 0; nn < 4; nn++) bf[nn] = *(const f16x8*)&Bs[cur][wc + nn * 16 + r0][q * 8];
#pragma unroll
    for (int m = 0; m < 4; m++)
#pragma unroll
      for (int nn = 0; nn < 4; nn++)
        acc[m][nn] = __builtin_amdgcn_mfma_f32_16x16x32_f16(af[m], bf[nn], acc[m][nn], 0, 0, 0);
    if (kk + 1 < kiters) CVTSTORE(cur ^ 1);
    __syncthreads();
  }

  f16* hout = p.h + (size_t)(z * 11 + slot) * B_ * D_;
#pragma unroll
  for (int nn = 0; nn < 4; nn++) {
    const int col = jbase + wc + nn * 16 + r0;
    const float bc = bias[col];
#pragma unroll
    for (int m = 0; m < 4; m++) {
#pragma unroll
      for (int i = 0; i < 4; i++) {
        int lr = mt * MT + wr + m * 16 + q * 4 + i;
        if (lr < row_cnt) {
          float v = acc[m][nn][i] + bc;
          v = v / (1.f + __expf(-v));
          hout[(size_t)(row_off + lr) * D_ + col] = (f16)v;
        }
      }
    }
  }
}

// ---------------------------------------------------------------- gate ------
struct GP {
  const f16* h;
  const float* gW2[2]; const float* gb2[2]; const float* temp[2];
  const int* dom;
  float* gates;
};

__global__ __launch_bounds__(256) void gate_kernel(GP p) {
  int wid = (blockIdx.x * 256 + threadIdx.x) >> 6;
  int lane = threadIdx.x & 63;
  int z = wid >> 11;
  int pos = wid & (B_ - 1);
  int n = p.dom[pos];
  const f16* gh = p.h + ((size_t)(z * 11 + 10) * B_ + pos) * D_;
  const float* W = p.gW2[z] + (size_t)n * D_ * NTOT;
  float part[NTOT];
#pragma unroll
  for (int e = 0; e < NTOT; e++) part[e] = 0.f;
  for (int k = lane; k < D_; k += 64) {
    float a = (float)gh[k];
    const float* wrow = W + (size_t)k * NTOT;
#pragma unroll
    for (int e = 0; e < NTOT; e++) part[e] = fmaf(a, wrow[e], part[e]);
  }
#pragma unroll
  for (int e = 0; e < NTOT; e++) {
    float v = part[e];
#pragma unroll
    for (int s = 32; s > 0; s >>= 1) v += __shfl_xor(v, s, 64);
    part[e] = v;
  }
  float tv = p.temp[z][n];
  float tq = (tv > 15.f ? tv : log1pf(__expf(tv))) + 1e-4f;
  const float* b2 = p.gb2[z] + n * NTOT;
  float mx = -1e30f;
#pragma unroll
  for (int e = 0; e < NTOT; e++) { part[e] = (part[e] + b2[e]) / tq; mx = fmaxf(mx, part[e]); }
  float s = 0.f;
#pragma unroll
  for (int e = 0; e < NTOT; e++) { part[e] = __expf(part[e] - mx); s += part[e]; }
  float inv = 1.f / s;
  if (lane < NTOT) p.gates[((size_t)z * B_ + pos) * NTOT + lane] = part[lane] * inv;
}

// ---------------------------------------------------------------- layer 2 ---
// grid: (96, 9, 10): z-dim = branch(2) x expert-pair(5); each block does 2 experts.
struct L2P {
  const f16* h;
  const float* W2[2]; const float* b2[2];
  const float* sW2[2]; const float* sb2[2];
  const float* gates;
  const int* perm; const int* off; const int* cnt;
  float* out;
};

__global__ __launch_bounds__(256, 3) void layer2_kernel(L2P p) {
  const int zz = blockIdx.z;
  const int z = zz / 5, es = zz % 5;
  const int ebase = es * 2;
  const int n = blockIdx.y;
  const int mt = blockIdx.x / NTILES, nt = blockIdx.x % NTILES;
  const int row_off = p.off[n], row_cnt = p.cnt[n];
  if (mt * MT >= row_cnt) return;

  __shared__ f16 As[2][MT][LDK];
  __shared__ f16 Bs[2][NT][LDK];
  __shared__ float sg[MT][2];
  __shared__ int sperm[MT];

  const int t = threadIdx.x;
  for (int i = t; i < MT * 2; i += 256) {
    int rr = i >> 1, e = i & 1;
    int gp = row_off + mt * MT + rr;
    sg[rr][e] = (gp < B_) ? p.gates[((size_t)z * B_ + gp) * NTOT + ebase + e] : 0.f;
  }
  for (int i = t; i < MT; i += 256) {
    int gp = row_off + mt * MT + i;
    sperm[i] = (gp < B_) ? p.perm[gp] : 0;
  }
  __syncthreads();

  const int wave = t >> 6, lane = t & 63;
  const int wr = (wave >> 1) * 64, wc = (wave & 1) * 64;
  const int r0 = lane & 15, q = lane >> 4;
  const int jbase = nt * NT;
  const int ar = t >> 1, akq = (t & 1) * 16;
  const int bj = (t >> 3) * 4, bk = (t & 7) * 4;

  int posr = row_off + mt * MT + ar;
  if (posr >= B_) posr = B_ - 1;

  const float* Wbase[2]; const float* pb[2]; float gsr[2];
#pragma unroll
  for (int ei = 0; ei < 2; ei++) {
    int e = ebase + ei;
    Wbase[ei] = (e < 6) ? (p.W2[z] + (size_t)(n * 6 + e) * D_ * D_)
                        : (p.sW2[z] + (size_t)(e - 6) * D_ * D_);
    pb[ei] = (e < 6) ? (p.b2[z] + (size_t)(n * 6 + e) * D_)
                     : (p.sb2[z] + (size_t)(e - 6) * D_);
    gsr[ei] = sg[ar][ei];
  }

  f16x8 h0, h1; f32x4 wv[4];
  auto LOAD = [&](int it) {
    const int ei = it / KI1;
    const int k0 = (it % KI1) * KT;
    const f16* hrow = p.h + ((size_t)(z * 11 + ebase + ei) * B_ + posr) * D_;
    h0 = *(const f16x8*)(hrow + k0 + akq);
    h1 = *(const f16x8*)(hrow + k0 + akq + 8);
#pragma unroll
    for (int i = 0; i < 4; i++)
      wv[i] = *(const f32x4*)(Wbase[ei] + (size_t)(k0 + bk + i) * D_ + jbase + bj);
  };
  auto CVTSTORE = [&](int buf, int it) {
    const int ei = it / KI1;
    const f16 gs = (f16)gsr[ei];
    f16x8 a0 = h0 * gs, a1 = h1 * gs;
    *(f16x8*)&As[buf][ar][akq]     = a0;
    *(f16x8*)&As[buf][ar][akq + 8] = a1;
#pragma unroll
    for (int j = 0; j < 4; j++) {
      union { f16x4 v; f16x2 p2[2]; } ub;
      ub.p2[0] = pkrtz(wv[0][j], wv[1][j]);
      ub.p2[1] = pkrtz(wv[2][j], wv[3][j]);
      *(f16x4*)&Bs[buf][bj + j][bk] = ub.v;
    }
  };

  f32x4 acc[4][4];
#pragma unroll
  for (int a = 0; a < 4; a++)
#pragma unroll
    for (int b = 0; b < 4; b++) acc[a][b] = (f32x4){0.f, 0.f, 0.f, 0.f};

  const int total = 2 * KI1;   // 48
  LOAD(0);
  CVTSTORE(0, 0);
  __syncthreads();

  for (int it = 0; it < total; it++) {
    const int cur = it & 1;
    if (it + 1 < total) LOAD(it + 1);
    f16x8 af[4], bf[4];
#pragma unroll
    for (int m = 0; m < 4; m++) af[m] = *(const f16x8*)&As[cur][wr + m * 16 + r0][q * 8];
#pragma unroll
    for (int nn = 0; nn < 4; nn++) bf[nn] = *(const f16x8*)&Bs[cur][wc + nn * 16 + r0][q * 8];
#pragma unroll
    for (int m = 0; m < 4; m++)
#pragma unroll
      for (int nn = 0; nn < 4; nn++)
        acc[m][nn] = __builtin_amdgcn_mfma_f32_16x16x32_f16(af[m], bf[nn], acc[m][nn], 0, 0, 0);
    if (it + 1 < total) CVTSTORE(cur ^ 1, it + 1);
    __syncthreads();
  }

  const int zoff = z * D_;
#pragma unroll
  for (int nn = 0; nn < 4; nn++) {
    const int col = jbase + wc + nn * 16 + r0;
    float pbc[2];
#pragma unroll
    for (int ei = 0; ei < 2; ei++) pbc[ei] = pb[ei][col];
#pragma unroll
    for (int m = 0; m < 4; m++) {
#pragma unroll
      for (int i = 0; i < 4; i++) {
        const int lrt = wr + m * 16 + q * 4 + i;
        if (mt * MT + lrt < row_cnt) {
          float v = acc[m][nn][i];
#pragma unroll
          for (int ei = 0; ei < 2; ei++) v = fmaf(sg[lrt][ei], pbc[ei], v);
          float* dst = p.out + (size_t)sperm[lrt] * (2 * D_) + zoff + col;
          __hip_atomic_fetch_add(dst, v, __ATOMIC_RELAXED, __HIP_MEMORY_SCOPE_AGENT);
        }
      }
    }
  }
}

// ---------------------------------------------------------------- launch ----
extern "C" void kernel_launch(void* const* d_in, const int* in_sizes, int n_in,
                              void* d_out, int out_size, void* d_ws, size_t ws_size,
                              hipStream_t stream) {
  const float* content = (const float*)d_in[0];
  const float* ftr     = (const float*)d_in[1];
  const int*   cat     = (const int*)d_in[2];
  const float* demb    = (const float*)d_in[3];

  const float* cW1  = (const float*)d_in[4];
  const float* cb1  = (const float*)d_in[5];
  const float* cW2  = (const float*)d_in[6];
  const float* cb2  = (const float*)d_in[7];
  const float* csW1 = (const float*)d_in[8];
  const float* csb1 = (const float*)d_in[9];
  const float* csW2 = (const float*)d_in[10];
  const float* csb2 = (const float*)d_in[11];
  const float* cgW1 = (const float*)d_in[12];
  const float* cgb1 = (const float*)d_in[13];
  const float* cgW2 = (const float*)d_in[14];
  const float* cgb2 = (const float*)d_in[15];
  const float* ctemp= (const float*)d_in[16];

  const float* fW1  = (const float*)d_in[17];
  const float* fb1  = (const float*)d_in[18];
  const float* fW2  = (const float*)d_in[19];
  const float* fb2  = (const float*)d_in[20];
  const float* fsW1 = (const float*)d_in[21];
  const float* fsb1 = (const float*)d_in[22];
  const float* fsW2 = (const float*)d_in[23];
  const float* fsb2 = (const float*)d_in[24];
  const float* fgW1 = (const float*)d_in[25];
  const float* fgb1 = (const float*)d_in[26];
  const float* fgW2 = (const float*)d_in[27];
  const float* fgb2 = (const float*)d_in[28];
  const float* ftemp= (const float*)d_in[29];

  char* wsb = (char*)d_ws;
  int* perm   = (int*)wsb;
  int* off    = (int*)(wsb + 8192);
  int* cnt    = (int*)(wsb + 8256);
  int* dom    = (int*)(wsb + 8320);
  float* gates= (float*)(wsb + 16512);
  f16* h      = (f16*)(wsb + 180352);
  float* out  = (float*)d_out;

  (void)hipMemsetAsync(d_out, 0, (size_t)out_size * sizeof(float), stream);

  bucket_kernel<<<1, 256, 0, stream>>>(cat, perm, off, cnt, dom);

  L1P p1;
  p1.x[0] = content; p1.x[1] = ftr;
  p1.W1[0] = cW1;  p1.W1[1] = fW1;  p1.b1[0] = cb1;  p1.b1[1] = fb1;
  p1.sW1[0] = csW1; p1.sW1[1] = fsW1; p1.sb1[0] = csb1; p1.sb1[1] = fsb1;
  p1.gW1[0] = cgW1; p1.gW1[1] = fgW1; p1.gb1[0] = cgb1; p1.gb1[1] = fgb1;
  p1.demb = demb; p1.perm = perm; p1.off = off; p1.cnt = cnt; p1.h = h;
  layer1_kernel<<<dim3(16 * NTILES, 67, 2), 256, 0, stream>>>(p1);

  GP pg;
  pg.h = h; pg.gW2[0] = cgW2; pg.gW2[1] = fgW2;
  pg.gb2[0] = cgb2; pg.gb2[1] = fgb2;
  pg.temp[0] = ctemp; pg.temp[1] = ftemp;
  pg.dom = dom; pg.gates = gates;
  gate_kernel<<<dim3((2 * B_) / 4), 256, 0, stream>>>(pg);

  L2P p2;
  p2.h = h;
  p2.W2[0] = cW2;  p2.W2[1] = fW2;  p2.b2[0] = cb2;  p2.b2[1] = fb2;
  p2.sW2[0] = csW2; p2.sW2[1] = fsW2; p2.sb2[0] = csb2; p2.sb2[1] = fsb2;
  p2.gates = gates; p2.perm = perm; p2.off = off; p2.cnt = cnt; p2.out = out;
  layer2_kernel<<<dim3(16 * NTILES, 9, 10), 256, 0, stream>>>(p2);

  (void)in_sizes; (void)n_in; (void)ws_size;
}

// Round 4
// 627.110 us; speedup vs baseline: 1.5894x; 1.5894x over previous
//
#include <hip/hip_runtime.h>

#define D_ 768
#define B_ 2048
#define NDOM 9
#define NTOT 10
#define MT 128
#define NT 128
#define KT 32
#define NTILES 6
#define KI1 (D_ / KT)   // 24

#define E2   589824ull        // 768*768
#define E2G  1179648ull       // 1536*768
#define OFF_WT2 31850496ull   // 54*E2
#define OFF_SW1 63700992ull   // 108*E2
#define OFF_SW2 66060288ull   // 112*E2
#define OFF_GW1 68419584ull   // 116*E2
#define ZWE     79036416ull   // OFF_GW1 + 9*E2G

typedef _Float16 f16;
typedef _Float16 f16x8 __attribute__((ext_vector_type(8)));
typedef _Float16 f16x2 __attribute__((ext_vector_type(2)));
typedef float f32x4 __attribute__((ext_vector_type(4)));

typedef const __attribute__((address_space(1))) void gas_void;
typedef __attribute__((address_space(3))) void las_void;

__device__ __forceinline__ void gload16(const f16* g, f16* l) {
  __builtin_amdgcn_global_load_lds((gas_void*)g, (las_void*)l, 16, 0, 0);
}

// ---------------------------------------------------------------- bucket ----
__global__ __launch_bounds__(256) void bucket_kernel(const int* cat32, int* perm,
                                                     int* off, int* cnt, int* dom) {
  __shared__ int scnt[NDOM], soff[NDOM], scur[NDOM];
  __shared__ int odd_nz;
  int t = threadIdx.x;
  if (t == 0) odd_nz = 0;
  if (t < NDOM) scnt[t] = 0;
  __syncthreads();
  int loc = 0;
  for (int i = t; i < B_; i += 256)
    if ((i & 1) && cat32[i] != 0) loc = 1;
  if (loc) atomicOr(&odd_nz, 1);
  __syncthreads();
  int strd = odd_nz ? 1 : 2;
  for (int i = t; i < B_; i += 256) atomicAdd(&scnt[cat32[i * strd]], 1);
  __syncthreads();
  if (t == 0) { int a = 0; for (int n = 0; n < NDOM; n++) { soff[n] = a; a += scnt[n]; } }
  __syncthreads();
  if (t < NDOM) { scur[t] = soff[t]; off[t] = soff[t]; cnt[t] = scnt[t]; }
  __syncthreads();
  for (int i = t; i < B_; i += 256) {
    int n = cat32[i * strd];
    int pos = atomicAdd(&scur[n], 1);
    perm[pos] = i;
    dom[pos] = n;
  }
}

// ---------------------------------------------------------------- cvt -------
__global__ __launch_bounds__(256) void cvt_kernel(const float* src, f16* dst, int n8) {
  int i = blockIdx.x * 256 + threadIdx.x;
  if (i >= n8) return;
  const f32x4* s = (const f32x4*)(src + (size_t)i * 8);
  f32x4 a = s[0], b = s[1];
  f16x8 o;
  o[0]=(f16)a[0]; o[1]=(f16)a[1]; o[2]=(f16)a[2]; o[3]=(f16)a[3];
  o[4]=(f16)b[0]; o[5]=(f16)b[1]; o[6]=(f16)b[2]; o[7]=(f16)b[3];
  *(f16x8*)(dst + (size_t)i * 8) = o;
}

// ------------------------------------------------------------ transpose -----
struct TRP { const float* s[10]; f16* wt; };

__global__ __launch_bounds__(256) void trans_kernel(TRP p) {
  const int m = blockIdx.z, z = m / 125, r = m % 125;
  const float* src; f16* dst; int R;
  const size_t zw = (size_t)z * ZWE;
  if (r < 54)       { src = p.s[0+z] + (size_t)r*E2;        dst = p.wt + zw + (size_t)r*E2;                 R = 768; }
  else if (r < 108) { int i=r-54;  src = p.s[2+z] + (size_t)i*E2;  dst = p.wt + zw + OFF_WT2 + (size_t)i*E2;  R = 768; }
  else if (r < 112) { int i=r-108; src = p.s[4+z] + (size_t)i*E2;  dst = p.wt + zw + OFF_SW1 + (size_t)i*E2;  R = 768; }
  else if (r < 116) { int i=r-112; src = p.s[6+z] + (size_t)i*E2;  dst = p.wt + zw + OFF_SW2 + (size_t)i*E2;  R = 768; }
  else              { int i=r-116; src = p.s[8+z] + (size_t)i*E2G; dst = p.wt + zw + OFF_GW1 + (size_t)i*E2G; R = 1536; }
  const int ty = blockIdx.y;
  if (ty * 64 >= R) return;
  const int tx = blockIdx.x;

  __shared__ f16 tile[64][72];
  const int t = threadIdx.x;
  const int lr = t >> 4, lc = (t & 15) * 4;
#pragma unroll
  for (int i = 0; i < 4; i++) {
    int row = lr + i * 16;
    f32x4 v = *(const f32x4*)(src + (size_t)(ty*64 + row) * 768 + tx*64 + lc);
    tile[lc+0][row] = (f16)v[0];
    tile[lc+1][row] = (f16)v[1];
    tile[lc+2][row] = (f16)v[2];
    tile[lc+3][row] = (f16)v[3];
  }
  __syncthreads();
  const int orow = t >> 3, oc = (t & 7) * 8;
#pragma unroll
  for (int i = 0; i < 2; i++) {
    int r2 = orow + i * 32;
    f16x8 v = *(const f16x8*)&tile[r2][oc];
    *(f16x8*)(dst + (size_t)(tx*64 + r2) * R + ty*64 + oc) = v;
  }
}

// ---------------------------------------------------------------- layer 1 ---
struct L1P {
  const f16* x16[2]; const f16* demb16; const f16* wt;
  const float* b1[2]; const float* sb1[2]; const float* gb1[2];
  const int* perm; const int* off; const int* cnt;
  f16* h;
};

__global__ __launch_bounds__(256, 4) void layer1_kernel(L1P p) {
  const int z = blockIdx.z;
  const int g = blockIdx.y;
  const int x = blockIdx.x;
  const int nt = x % 6;
  int mt0 = x / 6, mtstep = 4;

  int row_off, row_cnt, slot, gdom = 0, kiters = KI1;
  const f16* WT; const float* bias;
  bool isGate = false;
  const size_t zw = (size_t)z * ZWE;
  if (g < 54) {
    int n = g / 6, e = g % 6;
    row_off = p.off[n]; row_cnt = p.cnt[n];
    WT = p.wt + zw + (size_t)(n*6+e) * E2;
    bias = p.b1[z] + (n*6+e) * D_;
    slot = e;
  } else if (g < 70) {
    int s_ = g - 54, e = s_ >> 2;
    row_off = 0; row_cnt = B_;
    WT = p.wt + zw + OFF_SW1 + (size_t)e * E2;
    bias = p.sb1[z] + e * D_;
    slot = 6 + e;
    mt0 = x / 6 + 4 * (s_ & 3); mtstep = 16;
  } else {
    int n = g - 70;
    row_off = p.off[n]; row_cnt = p.cnt[n];
    WT = p.wt + zw + OFF_GW1 + (size_t)n * E2G;
    bias = p.gb1[z] + n * D_;
    slot = 10; isGate = true; gdom = n; kiters = 2 * KI1;
  }
  const int KW = isGate ? 2 * D_ : D_;

  __shared__ f16 As[2][MT][KT];
  __shared__ f16 Bs[2][MT][KT];

  const int t = threadIdx.x;
  const int wave = t >> 6, lane = t & 63;
  const int wr = (wave >> 1) * 64, wc = (wave & 1) * 64;
  const int r0 = lane & 15, q = lane >> 4;
  const int jbase = nt * NT;
  const int lrow = lane >> 2;
  const int lk = (lane & 3) * 8;

  const f16* bBase[2];
#pragma unroll
  for (int i = 0; i < 2; i++) {
    int col = jbase + 32 * wave + 16 * i + lrow;
    bBase[i] = WT + (size_t)col * KW + lk;
  }
  const f16* dB = p.demb16 + (size_t)gdom * D_ + lk;

  for (int mt = mt0; mt * MT < row_cnt; mt += mtstep) {
    const f16* aBase[2];
#pragma unroll
    for (int i = 0; i < 2; i++) {
      int rl = mt * MT + 32 * wave + 16 * i + lrow;
      int pr = p.perm[(rl < row_cnt) ? (row_off + rl) : row_off];
      aBase[i] = p.x16[z] + (size_t)pr * D_ + lk;
    }

    auto STAGE = [&](int buf, int kk) {
      const int k0 = kk * KT;
#pragma unroll
      for (int i = 0; i < 2; i++) {
        const f16* as;
        if (isGate) as = (k0 < D_) ? (dB + k0) : (aBase[i] + (k0 - D_));
        else        as = aBase[i] + k0;
        gload16(as, &As[buf][32 * wave + 16 * i][0]);
        gload16(bBase[i] + k0, &Bs[buf][32 * wave + 16 * i][0]);
      }
    };

    f32x4 acc[4][4];
#pragma unroll
    for (int a = 0; a < 4; a++)
#pragma unroll
      for (int b = 0; b < 4; b++) acc[a][b] = (f32x4){0.f, 0.f, 0.f, 0.f};

    STAGE(0, 0);
    __syncthreads();
    for (int kk = 0; kk < kiters; kk++) {
      const int cur = kk & 1;
      if (kk + 1 < kiters) STAGE(cur ^ 1, kk + 1);
      f16x8 af[4], bf[4];
#pragma unroll
      for (int m = 0; m < 4; m++) af[m] = *(const f16x8*)&As[cur][wr + m * 16 + r0][q * 8];
#pragma unroll
      for (int nn = 0; nn < 4; nn++) bf[nn] = *(const f16x8*)&Bs[cur][wc + nn * 16 + r0][q * 8];
#pragma unroll
      for (int m = 0; m < 4; m++)
#pragma unroll
        for (int nn = 0; nn < 4; nn++)
          acc[m][nn] = __builtin_amdgcn_mfma_f32_16x16x32_f16(af[m], bf[nn], acc[m][nn], 0, 0, 0);
      __syncthreads();
    }

    f16* hout = p.h + (size_t)(z * 11 + slot) * B_ * D_;
#pragma unroll
    for (int nn = 0; nn < 4; nn++) {
      const int col = jbase + wc + nn * 16 + r0;
      const float bc = bias[col];
#pragma unroll
      for (int m = 0; m < 4; m++) {
#pragma unroll
        for (int i = 0; i < 4; i++) {
          int lr = mt * MT + wr + m * 16 + q * 4 + i;
          if (lr < row_cnt) {
            float v = acc[m][nn][i] + bc;
            v = v / (1.f + __expf(-v));
            hout[(size_t)(row_off + lr) * D_ + col] = (f16)v;
          }
        }
      }
    }
  }
}

// ---------------------------------------------------------------- gate ------
struct GP {
  const f16* h;
  const float* gW2[2]; const float* gb2[2]; const float* temp[2];
  const int* dom;
  float* gates;
};

__global__ __launch_bounds__(256) void gate_kernel(GP p) {
  int wid = (blockIdx.x * 256 + threadIdx.x) >> 6;
  int lane = threadIdx.x & 63;
  int z = wid >> 11;
  int pos = wid & (B_ - 1);
  int n = p.dom[pos];
  const f16* gh = p.h + ((size_t)(z * 11 + 10) * B_ + pos) * D_;
  const float* W = p.gW2[z] + (size_t)n * D_ * NTOT;
  float part[NTOT];
#pragma unroll
  for (int e = 0; e < NTOT; e++) part[e] = 0.f;
  for (int k = lane; k < D_; k += 64) {
    float a = (float)gh[k];
    const float* wrow = W + (size_t)k * NTOT;
#pragma unroll
    for (int e = 0; e < NTOT; e++) part[e] = fmaf(a, wrow[e], part[e]);
  }
#pragma unroll
  for (int e = 0; e < NTOT; e++) {
    float v = part[e];
#pragma unroll
    for (int s = 32; s > 0; s >>= 1) v += __shfl_xor(v, s, 64);
    part[e] = v;
  }
  float tv = p.temp[z][n];
  float tq = (tv > 15.f ? tv : log1pf(__expf(tv))) + 1e-4f;
  const float* b2 = p.gb2[z] + n * NTOT;
  float mx = -1e30f;
#pragma unroll
  for (int e = 0; e < NTOT; e++) { part[e] = (part[e] + b2[e]) / tq; mx = fmaxf(mx, part[e]); }
  float s = 0.f;
#pragma unroll
  for (int e = 0; e < NTOT; e++) { part[e] = __expf(part[e] - mx); s += part[e]; }
  float inv = 1.f / s;
  if (lane < NTOT) p.gates[((size_t)z * B_ + pos) * NTOT + lane] = part[lane] * inv;
}

// ---------------------------------------------------------------- layer 2 ---
struct L2P {
  const f16* h; const f16* wt;
  const float* b2[2]; const float* sb2[2];
  const float* gates;
  const int* perm; const int* off; const int* cnt;
  float* out;
};

__global__ __launch_bounds__(256, 4) void layer2_kernel(L2P p) {
  const int zz = blockIdx.z;
  const int z = zz / 5, es = zz % 5, ebase = es * 2;
  const int n = blockIdx.y;
  const int x = blockIdx.x;
  const int nt = x % 6, mt0 = x / 6;
  const int row_off = p.off[n], row_cnt = p.cnt[n];

  __shared__ f16 As[2][MT][KT];
  __shared__ f16 Bs[2][MT][KT];
  __shared__ float sg[MT][2];
  __shared__ int sperm[MT];

  const int t = threadIdx.x;
  const int wave = t >> 6, lane = t & 63;
  const int wr = (wave >> 1) * 64, wc = (wave & 1) * 64;
  const int r0 = lane & 15, q = lane >> 4;
  const int jbase = nt * NT;
  const int lrow = lane >> 2;
  const int lk = (lane & 3) * 8;

  const size_t zw = (size_t)z * ZWE;
  const f16* WB0; const f16* WB1; const float* pb[2]; size_t slotOff[2];
  {
    int e0 = ebase, e1 = ebase + 1;
    WB0 = (e0 < 6) ? (p.wt + zw + OFF_WT2 + (size_t)(n*6+e0)*E2) : (p.wt + zw + OFF_SW2 + (size_t)(e0-6)*E2);
    WB1 = (e1 < 6) ? (p.wt + zw + OFF_WT2 + (size_t)(n*6+e1)*E2) : (p.wt + zw + OFF_SW2 + (size_t)(e1-6)*E2);
    pb[0] = (e0 < 6) ? (p.b2[z] + (size_t)(n*6+e0)*D_) : (p.sb2[z] + (size_t)(e0-6)*D_);
    pb[1] = (e1 < 6) ? (p.b2[z] + (size_t)(n*6+e1)*D_) : (p.sb2[z] + (size_t)(e1-6)*D_);
    slotOff[0] = (size_t)(z*11 + e0) * B_ * D_;
    slotOff[1] = (size_t)(z*11 + e1) * B_ * D_;
  }

  const f16* bB0[2]; const f16* bB1[2];
#pragma unroll
  for (int i = 0; i < 2; i++) {
    int col = jbase + 32 * wave + 16 * i + lrow;
    bB0[i] = WB0 + (size_t)col * D_ + lk;
    bB1[i] = WB1 + (size_t)col * D_ + lk;
  }

  for (int mt = mt0; mt * MT < row_cnt; mt += 4) {
    for (int i = t; i < MT * 2; i += 256) {
      int rr = i >> 1, e = i & 1;
      int gp = row_off + mt * MT + rr;
      sg[rr][e] = (gp < B_ && (mt * MT + rr) < row_cnt)
                  ? p.gates[((size_t)z * B_ + gp) * NTOT + ebase + e] : 0.f;
    }
    for (int i = t; i < MT; i += 256) {
      int gp = row_off + mt * MT + i;
      sperm[i] = (gp < B_) ? p.perm[gp] : 0;
    }
    __syncthreads();

    const f16* aB0[2]; const f16* aB1[2];
#pragma unroll
    for (int i = 0; i < 2; i++) {
      int rl = mt * MT + 32 * wave + 16 * i + lrow;
      int rr = (rl < row_cnt) ? (row_off + rl) : row_off;
      size_t rp = (size_t)rr * D_ + lk;
      aB0[i] = p.h + slotOff[0] + rp;
      aB1[i] = p.h + slotOff[1] + rp;
    }
    f16 gA[4], gB[4];
#pragma unroll
    for (int m = 0; m < 4; m++) {
      gA[m] = (f16)sg[wr + m * 16 + r0][0];
      gB[m] = (f16)sg[wr + m * 16 + r0][1];
    }

    auto STAGE = [&](int buf, int it) {
      const int ei = (it >= KI1);
      const int k0 = (it - (ei ? KI1 : 0)) * KT;
#pragma unroll
      for (int i = 0; i < 2; i++) {
        const f16* as = (ei ? aB1[i] : aB0[i]) + k0;
        const f16* bs = (ei ? bB1[i] : bB0[i]) + k0;
        gload16(as, &As[buf][32 * wave + 16 * i][0]);
        gload16(bs, &Bs[buf][32 * wave + 16 * i][0]);
      }
    };

    f32x4 acc[4][4];
#pragma unroll
    for (int a = 0; a < 4; a++)
#pragma unroll
      for (int b = 0; b < 4; b++) acc[a][b] = (f32x4){0.f, 0.f, 0.f, 0.f};

    const int total = 2 * KI1;
    STAGE(0, 0);
    __syncthreads();
    for (int it = 0; it < total; it++) {
      const int cur = it & 1;
      if (it + 1 < total) STAGE(cur ^ 1, it + 1);
      const int ei = (it >= KI1);
      f16x8 af[4], bf[4];
#pragma unroll
      for (int m = 0; m < 4; m++) {
        af[m] = *(const f16x8*)&As[cur][wr + m * 16 + r0][q * 8];
        af[m] = af[m] * (ei ? gB[m] : gA[m]);
      }
#pragma unroll
      for (int nn = 0; nn < 4; nn++) bf[nn] = *(const f16x8*)&Bs[cur][wc + nn * 16 + r0][q * 8];
#pragma unroll
      for (int m = 0; m < 4; m++)
#pragma unroll
        for (int nn = 0; nn < 4; nn++)
          acc[m][nn] = __builtin_amdgcn_mfma_f32_16x16x32_f16(af[m], bf[nn], acc[m][nn], 0, 0, 0);
      __syncthreads();
    }

    const int zoff = z * D_;
#pragma unroll
    for (int nn = 0; nn < 4; nn++) {
      const int col = jbase + wc + nn * 16 + r0;
      float pbc0 = pb[0][col], pbc1 = pb[1][col];
#pragma unroll
      for (int m = 0; m < 4; m++) {
#pragma unroll
        for (int i = 0; i < 4; i++) {
          const int lrt = wr + m * 16 + q * 4 + i;
          if (mt * MT + lrt < row_cnt) {
            float v = acc[m][nn][i];
            v = fmaf(sg[lrt][0], pbc0, v);
            v = fmaf(sg[lrt][1], pbc1, v);
            float* dst = p.out + (size_t)sperm[lrt] * (2 * D_) + zoff + col;
            __hip_atomic_fetch_add(dst, v, __ATOMIC_RELAXED, __HIP_MEMORY_SCOPE_AGENT);
          }
        }
      }
    }
    __syncthreads();
  }
}

// ---------------------------------------------------------------- launch ----
extern "C" void kernel_launch(void* const* d_in, const int* in_sizes, int n_in,
                              void* d_out, int out_size, void* d_ws, size_t ws_size,
                              hipStream_t stream) {
  const float* content = (const float*)d_in[0];
  const float* ftr     = (const float*)d_in[1];
  const int*   cat     = (const int*)d_in[2];
  const float* demb    = (const float*)d_in[3];

  const float* cW1  = (const float*)d_in[4];
  const float* cb1  = (const float*)d_in[5];
  const float* cW2  = (const float*)d_in[6];
  const float* cb2  = (const float*)d_in[7];
  const float* csW1 = (const float*)d_in[8];
  const float* csb1 = (const float*)d_in[9];
  const float* csW2 = (const float*)d_in[10];
  const float* csb2 = (const float*)d_in[11];
  const float* cgW1 = (const float*)d_in[12];
  const float* cgb1 = (const float*)d_in[13];
  const float* cgW2 = (const float*)d_in[14];
  const float* cgb2 = (const float*)d_in[15];
  const float* ctemp= (const float*)d_in[16];

  const float* fW1  = (const float*)d_in[17];
  const float* fb1  = (const float*)d_in[18];
  const float* fW2  = (const float*)d_in[19];
  const float* fb2  = (const float*)d_in[20];
  const float* fsW1 = (const float*)d_in[21];
  const float* fsb1 = (const float*)d_in[22];
  const float* fsW2 = (const float*)d_in[23];
  const float* fsb2 = (const float*)d_in[24];
  const float* fgW1 = (const float*)d_in[25];
  const float* fgb1 = (const float*)d_in[26];
  const float* fgW2 = (const float*)d_in[27];
  const float* fgb2 = (const float*)d_in[28];
  const float* ftemp= (const float*)d_in[29];

  char* wsb = (char*)d_ws;
  int* perm    = (int*)wsb;                        // 8 KB
  int* off     = (int*)(wsb + 8192);
  int* cnt     = (int*)(wsb + 8256);
  int* dom     = (int*)(wsb + 8320);               // 8 KB
  float* gates = (float*)(wsb + 16512);            // 160 KB
  f16* h       = (f16*)(wsb + 180352);             // 66 MB
  f16* x16a    = (f16*)(wsb + 69386368);           // 3 MB
  f16* x16b    = (f16*)(wsb + 72532096);           // 3 MB
  f16* demb16  = (f16*)(wsb + 75677824);           // 13.5 KB
  f16* wt      = (f16*)(wsb + 75691648);           // 316 MB
  float* out   = (float*)d_out;

  (void)hipMemsetAsync(d_out, 0, (size_t)out_size * sizeof(float), stream);

  bucket_kernel<<<1, 256, 0, stream>>>(cat, perm, off, cnt, dom);

  cvt_kernel<<<768, 256, 0, stream>>>(content, x16a, (B_ * D_) / 8);
  cvt_kernel<<<768, 256, 0, stream>>>(ftr, x16b, (B_ * D_) / 8);
  cvt_kernel<<<4, 256, 0, stream>>>(demb, demb16, (NDOM * D_) / 8);

  TRP tp;
  tp.s[0] = cW1;  tp.s[1] = fW1;
  tp.s[2] = cW2;  tp.s[3] = fW2;
  tp.s[4] = csW1; tp.s[5] = fsW1;
  tp.s[6] = csW2; tp.s[7] = fsW2;
  tp.s[8] = cgW1; tp.s[9] = fgW1;
  tp.wt = wt;
  trans_kernel<<<dim3(12, 24, 250), 256, 0, stream>>>(tp);

  L1P p1;
  p1.x16[0] = x16a; p1.x16[1] = x16b; p1.demb16 = demb16; p1.wt = wt;
  p1.b1[0] = cb1;  p1.b1[1] = fb1;
  p1.sb1[0] = csb1; p1.sb1[1] = fsb1;
  p1.gb1[0] = cgb1; p1.gb1[1] = fgb1;
  p1.perm = perm; p1.off = off; p1.cnt = cnt; p1.h = h;
  layer1_kernel<<<dim3(24, 79, 2), 256, 0, stream>>>(p1);

  GP pg;
  pg.h = h; pg.gW2[0] = cgW2; pg.gW2[1] = fgW2;
  pg.gb2[0] = cgb2; pg.gb2[1] = fgb2;
  pg.temp[0] = ctemp; pg.temp[1] = ftemp;
  pg.dom = dom; pg.gates = gates;
  gate_kernel<<<dim3((2 * B_) / 4), 256, 0, stream>>>(pg);

  L2P p2;
  p2.h = h; p2.wt = wt;
  p2.b2[0] = cb2;  p2.b2[1] = fb2;
  p2.sb2[0] = csb2; p2.sb2[1] = fsb2;
  p2.gates = gates; p2.perm = perm; p2.off = off; p2.cnt = cnt; p2.out = out;
  layer2_kernel<<<dim3(24, 9, 10), 256, 0, stream>>>(p2);

  (void)in_sizes; (void)n_in; (void)ws_size;
}

// Round 5
// 612.486 us; speedup vs baseline: 1.6274x; 1.0239x over previous
//
#include <hip/hip_runtime.h>

#define D_ 768
#define B_ 2048
#define NDOM 9
#define NTOT 10
#define MT 128
#define NT 128
#define KT 32
#define KI1 (D_ / KT)   // 24

#define E2   589824ull        // 768*768
#define E2G  1179648ull       // 1536*768
#define OFF_WT2 31850496ull   // 54*E2
#define OFF_SW1 63700992ull   // 108*E2
#define OFF_SW2 66060288ull   // 112*E2
#define OFF_GW1 68419584ull   // 116*E2
#define ZWE     79036416ull   // OFF_GW1 + 9*E2G

typedef _Float16 f16;
typedef _Float16 f16x8 __attribute__((ext_vector_type(8)));
typedef _Float16 f16x2 __attribute__((ext_vector_type(2)));
typedef float f32x4 __attribute__((ext_vector_type(4)));

typedef const __attribute__((address_space(1))) void gas_void;
typedef __attribute__((address_space(3))) void las_void;

__device__ __forceinline__ void gload16(const f16* g, f16* l) {
  __builtin_amdgcn_global_load_lds((gas_void*)g, (las_void*)l, 16, 0, 0);
}

#define WAITV4() asm volatile("s_waitcnt vmcnt(4)" ::: "memory")
#define WAITV0() asm volatile("s_waitcnt vmcnt(0)" ::: "memory")
#define SBAR()   do { __builtin_amdgcn_s_barrier(); __builtin_amdgcn_sched_barrier(0); } while (0)

// ---------------------------------------------------------------- bucket ----
__global__ __launch_bounds__(256) void bucket_kernel(const int* cat32, int* perm,
                                                     int* off, int* cnt, int* dom) {
  __shared__ int scnt[NDOM], soff[NDOM], scur[NDOM];
  __shared__ int odd_nz;
  int t = threadIdx.x;
  if (t == 0) odd_nz = 0;
  if (t < NDOM) scnt[t] = 0;
  __syncthreads();
  int loc = 0;
  for (int i = t; i < B_; i += 256)
    if ((i & 1) && cat32[i] != 0) loc = 1;
  if (loc) atomicOr(&odd_nz, 1);
  __syncthreads();
  int strd = odd_nz ? 1 : 2;
  for (int i = t; i < B_; i += 256) atomicAdd(&scnt[cat32[i * strd]], 1);
  __syncthreads();
  if (t == 0) { int a = 0; for (int n = 0; n < NDOM; n++) { soff[n] = a; a += scnt[n]; } }
  __syncthreads();
  if (t < NDOM) { scur[t] = soff[t]; off[t] = soff[t]; cnt[t] = scnt[t]; }
  __syncthreads();
  for (int i = t; i < B_; i += 256) {
    int n = cat32[i * strd];
    int pos = atomicAdd(&scur[n], 1);
    perm[pos] = i;
    dom[pos] = n;
  }
}

// ---------------------------------------------------------------- cvt -------
__global__ __launch_bounds__(256) void cvt_kernel(const float* src, f16* dst, int n8) {
  int i = blockIdx.x * 256 + threadIdx.x;
  if (i >= n8) return;
  const f32x4* s = (const f32x4*)(src + (size_t)i * 8);
  f32x4 a = s[0], b = s[1];
  f16x8 o;
  o[0]=(f16)a[0]; o[1]=(f16)a[1]; o[2]=(f16)a[2]; o[3]=(f16)a[3];
  o[4]=(f16)b[0]; o[5]=(f16)b[1]; o[6]=(f16)b[2]; o[7]=(f16)b[3];
  *(f16x8*)(dst + (size_t)i * 8) = o;
}

// ------------------------------------------------------------ transpose -----
struct TRP { const float* s[10]; f16* wt; };

__global__ __launch_bounds__(256) void trans_kernel(TRP p) {
  const int m = blockIdx.z, z = m / 125, r = m % 125;
  const float* src; f16* dst; int R;
  const size_t zw = (size_t)z * ZWE;
  if (r < 54)       { src = p.s[0+z] + (size_t)r*E2;        dst = p.wt + zw + (size_t)r*E2;                 R = 768; }
  else if (r < 108) { int i=r-54;  src = p.s[2+z] + (size_t)i*E2;  dst = p.wt + zw + OFF_WT2 + (size_t)i*E2;  R = 768; }
  else if (r < 112) { int i=r-108; src = p.s[4+z] + (size_t)i*E2;  dst = p.wt + zw + OFF_SW1 + (size_t)i*E2;  R = 768; }
  else if (r < 116) { int i=r-112; src = p.s[6+z] + (size_t)i*E2;  dst = p.wt + zw + OFF_SW2 + (size_t)i*E2;  R = 768; }
  else              { int i=r-116; src = p.s[8+z] + (size_t)i*E2G; dst = p.wt + zw + OFF_GW1 + (size_t)i*E2G; R = 1536; }
  const int ty = blockIdx.y;
  if (ty * 64 >= R) return;
  const int tx = blockIdx.x;

  __shared__ f16 tile[64][72];
  const int t = threadIdx.x;
  const int lr = t >> 4, lc = (t & 15) * 4;
#pragma unroll
  for (int i = 0; i < 4; i++) {
    int row = lr + i * 16;
    f32x4 v = *(const f32x4*)(src + (size_t)(ty*64 + row) * 768 + tx*64 + lc);
    tile[lc+0][row] = (f16)v[0];
    tile[lc+1][row] = (f16)v[1];
    tile[lc+2][row] = (f16)v[2];
    tile[lc+3][row] = (f16)v[3];
  }
  __syncthreads();
  const int orow = t >> 3, oc = (t & 7) * 8;
#pragma unroll
  for (int i = 0; i < 2; i++) {
    int r2 = orow + i * 32;
    f16x8 v = *(const f16x8*)&tile[r2][oc];
    *(f16x8*)(dst + (size_t)(tx*64 + r2) * R + ty*64 + oc) = v;
  }
}

// ---------------------------------------------------------------- layer 1 ---
struct L1P {
  const f16* x16[2]; const f16* demb16; const f16* wt;
  const float* b1[2]; const float* sb1[2]; const float* gb1[2];
  const int* perm; const int* off; const int* cnt;
  f16* h;
};

__global__ __launch_bounds__(256, 3) void layer1_kernel(L1P p) {
  const int z = blockIdx.z;
  const int g = blockIdx.y;
  const int x = blockIdx.x;
  const int nt = x % 6;
  int mt0 = x / 6, mtstep = 4;

  int row_off, row_cnt, slot, gdom = 0, kiters = KI1;
  const f16* WT; const float* bias;
  bool isGate = false;
  const size_t zw = (size_t)z * ZWE;
  if (g < 54) {
    int n = g / 6, e = g % 6;
    row_off = p.off[n]; row_cnt = p.cnt[n];
    WT = p.wt + zw + (size_t)(n*6+e) * E2;
    bias = p.b1[z] + (n*6+e) * D_;
    slot = e;
  } else if (g < 70) {
    int s_ = g - 54, e = s_ >> 2;
    row_off = 0; row_cnt = B_;
    WT = p.wt + zw + OFF_SW1 + (size_t)e * E2;
    bias = p.sb1[z] + e * D_;
    slot = 6 + e;
    mt0 = x / 6 + 4 * (s_ & 3); mtstep = 16;
  } else {
    int n = g - 70;
    row_off = p.off[n]; row_cnt = p.cnt[n];
    WT = p.wt + zw + OFF_GW1 + (size_t)n * E2G;
    bias = p.gb1[z] + n * D_;
    slot = 10; isGate = true; gdom = n; kiters = 2 * KI1;
  }
  const int KW = isGate ? 2 * D_ : D_;

  __shared__ f16 As[3][MT][KT];
  __shared__ f16 Bs[3][MT][KT];

  const int t = threadIdx.x;
  const int wave = t >> 6, lane = t & 63;
  const int wr = (wave >> 1) * 64, wc = (wave & 1) * 64;
  const int r0 = lane & 15, q = lane >> 4;
  const int jbase = nt * NT;
  const int lrow = lane >> 2;
  const int lk = (lane & 3) * 8;

  const f16* bBase[2];
#pragma unroll
  for (int i = 0; i < 2; i++) {
    int col = jbase + 32 * wave + 16 * i + lrow;
    bBase[i] = WT + (size_t)col * KW + lk;
  }
  const f16* dB = p.demb16 + (size_t)gdom * D_ + lk;

  for (int mt = mt0; mt * MT < row_cnt; mt += mtstep) {
    const f16* aBase[2];
#pragma unroll
    for (int i = 0; i < 2; i++) {
      int rl = mt * MT + 32 * wave + 16 * i + lrow;
      int pr = p.perm[(rl < row_cnt) ? (row_off + rl) : row_off];
      aBase[i] = p.x16[z] + (size_t)pr * D_ + lk;
    }

    auto STAGE = [&](int buf, int kk) {
      const int k0 = kk * KT;
#pragma unroll
      for (int i = 0; i < 2; i++) {
        const f16* as;
        if (isGate) as = (k0 < D_) ? (dB + k0) : (aBase[i] + (k0 - D_));
        else        as = aBase[i] + k0;
        gload16(as, &As[buf][32 * wave + 16 * i][0]);
        gload16(bBase[i] + k0, &Bs[buf][32 * wave + 16 * i][0]);
      }
    };

    f32x4 acc[4][4];
#pragma unroll
    for (int a = 0; a < 4; a++)
#pragma unroll
      for (int b = 0; b < 4; b++) acc[a][b] = (f32x4){0.f, 0.f, 0.f, 0.f};

    STAGE(0, 0);
    STAGE(1, 1);
    WAITV4();           // tile0 landed; tile1 in flight
    SBAR();

    int cur = 0;
    for (int kk = 0; kk < kiters; kk++) {
      int pf = cur + 2; if (pf >= 3) pf -= 3;
      if (kk + 2 < kiters) STAGE(pf, kk + 2);
      f16x8 af[4], bf[4];
#pragma unroll
      for (int m = 0; m < 4; m++) af[m] = *(const f16x8*)&As[cur][wr + m * 16 + r0][q * 8];
#pragma unroll
      for (int nn = 0; nn < 4; nn++) bf[nn] = *(const f16x8*)&Bs[cur][wc + nn * 16 + r0][q * 8];
#pragma unroll
      for (int m = 0; m < 4; m++)
#pragma unroll
        for (int nn = 0; nn < 4; nn++)
          acc[m][nn] = __builtin_amdgcn_mfma_f32_16x16x32_f16(af[m], bf[nn], acc[m][nn], 0, 0, 0);
      if (kk + 2 < kiters) { WAITV4(); } else { WAITV0(); }
      SBAR();
      cur = (cur == 2) ? 0 : cur + 1;
    }

    f16* hout = p.h + (size_t)(z * 11 + slot) * B_ * D_;
#pragma unroll
    for (int nn = 0; nn < 4; nn++) {
      const int col = jbase + wc + nn * 16 + r0;
      const float bc = bias[col];
#pragma unroll
      for (int m = 0; m < 4; m++) {
#pragma unroll
        for (int i = 0; i < 4; i++) {
          int lr = mt * MT + wr + m * 16 + q * 4 + i;
          if (lr < row_cnt) {
            float v = acc[m][nn][i] + bc;
            v = v / (1.f + __expf(-v));
            hout[(size_t)(row_off + lr) * D_ + col] = (f16)v;
          }
        }
      }
    }
  }
}

// ---------------------------------------------------------------- gate ------
struct GP {
  const f16* h;
  const float* gW2[2]; const float* gb2[2]; const float* temp[2];
  const int* dom;
  float* gates;
};

__global__ __launch_bounds__(256) void gate_kernel(GP p) {
  int wid = (blockIdx.x * 256 + threadIdx.x) >> 6;
  int lane = threadIdx.x & 63;
  int z = wid >> 11;
  int pos = wid & (B_ - 1);
  int n = p.dom[pos];
  const f16* gh = p.h + ((size_t)(z * 11 + 10) * B_ + pos) * D_;
  const float* W = p.gW2[z] + (size_t)n * D_ * NTOT;
  float part[NTOT];
#pragma unroll
  for (int e = 0; e < NTOT; e++) part[e] = 0.f;
  for (int k = lane; k < D_; k += 64) {
    float a = (float)gh[k];
    const float* wrow = W + (size_t)k * NTOT;
#pragma unroll
    for (int e = 0; e < NTOT; e++) part[e] = fmaf(a, wrow[e], part[e]);
  }
#pragma unroll
  for (int e = 0; e < NTOT; e++) {
    float v = part[e];
#pragma unroll
    for (int s = 32; s > 0; s >>= 1) v += __shfl_xor(v, s, 64);
    part[e] = v;
  }
  float tv = p.temp[z][n];
  float tq = (tv > 15.f ? tv : log1pf(__expf(tv))) + 1e-4f;
  const float* b2 = p.gb2[z] + n * NTOT;
  float mx = -1e30f;
#pragma unroll
  for (int e = 0; e < NTOT; e++) { part[e] = (part[e] + b2[e]) / tq; mx = fmaxf(mx, part[e]); }
  float s = 0.f;
#pragma unroll
  for (int e = 0; e < NTOT; e++) { part[e] = __expf(part[e] - mx); s += part[e]; }
  float inv = 1.f / s;
  if (lane < NTOT) p.gates[((size_t)z * B_ + pos) * NTOT + lane] = part[lane] * inv;
}

// ---------------------------------------------------------------- layer 2 ---
struct L2P {
  const f16* h; const f16* wt;
  const float* b2[2]; const float* sb2[2];
  const float* gates;
  const int* perm; const int* off; const int* cnt;
  float* out;
};

__global__ __launch_bounds__(256, 3) void layer2_kernel(L2P p) {
  const int zz = blockIdx.z;
  const int z = zz / 5, es = zz % 5, ebase = es * 2;
  const int n = blockIdx.y;
  const int x = blockIdx.x;
  const int nt = x % 6, mt0 = x / 6;
  const int row_off = p.off[n], row_cnt = p.cnt[n];

  __shared__ f16 As[3][MT][KT];
  __shared__ f16 Bs[3][MT][KT];
  __shared__ float sg[MT][2];
  __shared__ int sperm[MT];

  const int t = threadIdx.x;
  const int wave = t >> 6, lane = t & 63;
  const int wr = (wave >> 1) * 64, wc = (wave & 1) * 64;
  const int r0 = lane & 15, q = lane >> 4;
  const int jbase = nt * NT;
  const int lrow = lane >> 2;
  const int lk = (lane & 3) * 8;

  const size_t zw = (size_t)z * ZWE;
  const f16* WB0; const f16* WB1; const float* pb[2]; size_t slotOff[2];
  {
    int e0 = ebase, e1 = ebase + 1;
    WB0 = (e0 < 6) ? (p.wt + zw + OFF_WT2 + (size_t)(n*6+e0)*E2) : (p.wt + zw + OFF_SW2 + (size_t)(e0-6)*E2);
    WB1 = (e1 < 6) ? (p.wt + zw + OFF_WT2 + (size_t)(n*6+e1)*E2) : (p.wt + zw + OFF_SW2 + (size_t)(e1-6)*E2);
    pb[0] = (e0 < 6) ? (p.b2[z] + (size_t)(n*6+e0)*D_) : (p.sb2[z] + (size_t)(e0-6)*D_);
    pb[1] = (e1 < 6) ? (p.b2[z] + (size_t)(n*6+e1)*D_) : (p.sb2[z] + (size_t)(e1-6)*D_);
    slotOff[0] = (size_t)(z*11 + e0) * B_ * D_;
    slotOff[1] = (size_t)(z*11 + e1) * B_ * D_;
  }

  const f16* bB0[2]; const f16* bB1[2];
#pragma unroll
  for (int i = 0; i < 2; i++) {
    int col = jbase + 32 * wave + 16 * i + lrow;
    bB0[i] = WB0 + (size_t)col * D_ + lk;
    bB1[i] = WB1 + (size_t)col * D_ + lk;
  }

  for (int mt = mt0; mt * MT < row_cnt; mt += 4) {
    for (int i = t; i < MT * 2; i += 256) {
      int rr = i >> 1, e = i & 1;
      int gp = row_off + mt * MT + rr;
      sg[rr][e] = (gp < B_ && (mt * MT + rr) < row_cnt)
                  ? p.gates[((size_t)z * B_ + gp) * NTOT + ebase + e] : 0.f;
    }
    for (int i = t; i < MT; i += 256) {
      int gp = row_off + mt * MT + i;
      sperm[i] = (gp < B_) ? p.perm[gp] : 0;
    }
    __syncthreads();

    const f16* aB0[2]; const f16* aB1[2];
#pragma unroll
    for (int i = 0; i < 2; i++) {
      int rl = mt * MT + 32 * wave + 16 * i + lrow;
      int rr = (rl < row_cnt) ? (row_off + rl) : row_off;
      size_t rp = (size_t)rr * D_ + lk;
      aB0[i] = p.h + slotOff[0] + rp;
      aB1[i] = p.h + slotOff[1] + rp;
    }
    f16 gA[4], gB[4];
#pragma unroll
    for (int m = 0; m < 4; m++) {
      gA[m] = (f16)sg[wr + m * 16 + r0][0];
      gB[m] = (f16)sg[wr + m * 16 + r0][1];
    }

    auto STAGE = [&](int buf, int it) {
      const int ei = (it >= KI1);
      const int k0 = (it - (ei ? KI1 : 0)) * KT;
#pragma unroll
      for (int i = 0; i < 2; i++) {
        const f16* as = (ei ? aB1[i] : aB0[i]) + k0;
        const f16* bs = (ei ? bB1[i] : bB0[i]) + k0;
        gload16(as, &As[buf][32 * wave + 16 * i][0]);
        gload16(bs, &Bs[buf][32 * wave + 16 * i][0]);
      }
    };

    f32x4 acc[4][4];
#pragma unroll
    for (int a = 0; a < 4; a++)
#pragma unroll
      for (int b = 0; b < 4; b++) acc[a][b] = (f32x4){0.f, 0.f, 0.f, 0.f};

    const int total = 2 * KI1;   // 48
    STAGE(0, 0);
    STAGE(1, 1);
    WAITV4();
    SBAR();

    int cur = 0;
    for (int it = 0; it < total; it++) {
      int pf = cur + 2; if (pf >= 3) pf -= 3;
      if (it + 2 < total) STAGE(pf, it + 2);
      const int ei = (it >= KI1);
      f16x8 af[4], bf[4];
#pragma unroll
      for (int m = 0; m < 4; m++) {
        af[m] = *(const f16x8*)&As[cur][wr + m * 16 + r0][q * 8];
        af[m] = af[m] * (ei ? gB[m] : gA[m]);
      }
#pragma unroll
      for (int nn = 0; nn < 4; nn++) bf[nn] = *(const f16x8*)&Bs[cur][wc + nn * 16 + r0][q * 8];
#pragma unroll
      for (int m = 0; m < 4; m++)
#pragma unroll
        for (int nn = 0; nn < 4; nn++)
          acc[m][nn] = __builtin_amdgcn_mfma_f32_16x16x32_f16(af[m], bf[nn], acc[m][nn], 0, 0, 0);
      if (it + 2 < total) { WAITV4(); } else { WAITV0(); }
      SBAR();
      cur = (cur == 2) ? 0 : cur + 1;
    }

    const int zoff = z * D_;
#pragma unroll
    for (int nn = 0; nn < 4; nn++) {
      const int col = jbase + wc + nn * 16 + r0;
      float pbc0 = pb[0][col], pbc1 = pb[1][col];
#pragma unroll
      for (int m = 0; m < 4; m++) {
#pragma unroll
        for (int i = 0; i < 4; i++) {
          const int lrt = wr + m * 16 + q * 4 + i;
          if (mt * MT + lrt < row_cnt) {
            float v = acc[m][nn][i];
            v = fmaf(sg[lrt][0], pbc0, v);
            v = fmaf(sg[lrt][1], pbc1, v);
            float* dst = p.out + (size_t)sperm[lrt] * (2 * D_) + zoff + col;
            __hip_atomic_fetch_add(dst, v, __ATOMIC_RELAXED, __HIP_MEMORY_SCOPE_AGENT);
          }
        }
      }
    }
    __syncthreads();
  }
}

// ---------------------------------------------------------------- launch ----
extern "C" void kernel_launch(void* const* d_in, const int* in_sizes, int n_in,
                              void* d_out, int out_size, void* d_ws, size_t ws_size,
                              hipStream_t stream) {
  const float* content = (const float*)d_in[0];
  const float* ftr     = (const float*)d_in[1];
  const int*   cat     = (const int*)d_in[2];
  const float* demb    = (const float*)d_in[3];

  const float* cW1  = (const float*)d_in[4];
  const float* cb1  = (const float*)d_in[5];
  const float* cW2  = (const float*)d_in[6];
  const float* cb2  = (const float*)d_in[7];
  const float* csW1 = (const float*)d_in[8];
  const float* csb1 = (const float*)d_in[9];
  const float* csW2 = (const float*)d_in[10];
  const float* csb2 = (const float*)d_in[11];
  const float* cgW1 = (const float*)d_in[12];
  const float* cgb1 = (const float*)d_in[13];
  const float* cgW2 = (const float*)d_in[14];
  const float* cgb2 = (const float*)d_in[15];
  const float* ctemp= (const float*)d_in[16];

  const float* fW1  = (const float*)d_in[17];
  const float* fb1  = (const float*)d_in[18];
  const float* fW2  = (const float*)d_in[19];
  const float* fb2  = (const float*)d_in[20];
  const float* fsW1 = (const float*)d_in[21];
  const float* fsb1 = (const float*)d_in[22];
  const float* fsW2 = (const float*)d_in[23];
  const float* fsb2 = (const float*)d_in[24];
  const float* fgW1 = (const float*)d_in[25];
  const float* fgb1 = (const float*)d_in[26];
  const float* fgW2 = (const float*)d_in[27];
  const float* fgb2 = (const float*)d_in[28];
  const float* ftemp= (const float*)d_in[29];

  char* wsb = (char*)d_ws;
  int* perm    = (int*)wsb;                        // 8 KB
  int* off     = (int*)(wsb + 8192);
  int* cnt     = (int*)(wsb + 8256);
  int* dom     = (int*)(wsb + 8320);               // 8 KB
  float* gates = (float*)(wsb + 16512);            // 160 KB
  f16* h       = (f16*)(wsb + 180352);             // 66 MB
  f16* x16a    = (f16*)(wsb + 69386368);           // 3 MB
  f16* x16b    = (f16*)(wsb + 72532096);           // 3 MB
  f16* demb16  = (f16*)(wsb + 75677824);           // 13.5 KB
  f16* wt      = (f16*)(wsb + 75691648);           // 316 MB
  float* out   = (float*)d_out;

  (void)hipMemsetAsync(d_out, 0, (size_t)out_size * sizeof(float), stream);

  bucket_kernel<<<1, 256, 0, stream>>>(cat, perm, off, cnt, dom);

  cvt_kernel<<<768, 256, 0, stream>>>(content, x16a, (B_ * D_) / 8);
  cvt_kernel<<<768, 256, 0, stream>>>(ftr, x16b, (B_ * D_) / 8);
  cvt_kernel<<<4, 256, 0, stream>>>(demb, demb16, (NDOM * D_) / 8);

  TRP tp;
  tp.s[0] = cW1;  tp.s[1] = fW1;
  tp.s[2] = cW2;  tp.s[3] = fW2;
  tp.s[4] = csW1; tp.s[5] = fsW1;
  tp.s[6] = csW2; tp.s[7] = fsW2;
  tp.s[8] = cgW1; tp.s[9] = fgW1;
  tp.wt = wt;
  trans_kernel<<<dim3(12, 24, 250), 256, 0, stream>>>(tp);

  L1P p1;
  p1.x16[0] = x16a; p1.x16[1] = x16b; p1.demb16 = demb16; p1.wt = wt;
  p1.b1[0] = cb1;  p1.b1[1] = fb1;
  p1.sb1[0] = csb1; p1.sb1[1] = fsb1;
  p1.gb1[0] = cgb1; p1.gb1[1] = fgb1;
  p1.perm = perm; p1.off = off; p1.cnt = cnt; p1.h = h;
  layer1_kernel<<<dim3(24, 79, 2), 256, 0, stream>>>(p1);

  GP pg;
  pg.h = h; pg.gW2[0] = cgW2; pg.gW2[1] = fgW2;
  pg.gb2[0] = cgb2; pg.gb2[1] = fgb2;
  pg.temp[0] = ctemp; pg.temp[1] = ftemp;
  pg.dom = dom; pg.gates = gates;
  gate_kernel<<<dim3((2 * B_) / 4), 256, 0, stream>>>(pg);

  L2P p2;
  p2.h = h; p2.wt = wt;
  p2.b2[0] = cb2;  p2.b2[1] = fb2;
  p2.sb2[0] = csb2; p2.sb2[1] = fsb2;
  p2.gates = gates; p2.perm = perm; p2.off = off; p2.cnt = cnt; p2.out = out;
  layer2_kernel<<<dim3(24, 9, 10), 256, 0, stream>>>(p2);

  (void)in_sizes; (void)n_in; (void)ws_size;
}

// Round 6
// 582.298 us; speedup vs baseline: 1.7117x; 1.0518x over previous
//
#include <hip/hip_runtime.h>

#define D_ 768
#define B_ 2048
#define NDOM 9
#define NTOT 10
#define MT 128
#define NT 128
#define KT 32
#define KI1 (D_ / KT)   // 24

#define E2   589824ull        // 768*768
#define E2G  1179648ull       // 1536*768
#define OFF_WT2 31850496ull   // 54*E2
#define OFF_SW1 63700992ull   // 108*E2
#define OFF_SW2 66060288ull   // 112*E2
#define OFF_GW1 68419584ull   // 116*E2
#define ZWE     79036416ull   // OFF_GW1 + 9*E2G

typedef _Float16 f16;
typedef _Float16 f16x8 __attribute__((ext_vector_type(8)));
typedef _Float16 f16x4 __attribute__((ext_vector_type(4)));
typedef _Float16 f16x2 __attribute__((ext_vector_type(2)));
typedef float f32x4 __attribute__((ext_vector_type(4)));

typedef const __attribute__((address_space(1))) void gas_void;
typedef __attribute__((address_space(3))) void las_void;

__device__ __forceinline__ void gload16(const f16* g, f16* l) {
  __builtin_amdgcn_global_load_lds((gas_void*)g, (las_void*)l, 16, 0, 0);
}

#define WAITV4() asm volatile("s_waitcnt vmcnt(4)" ::: "memory")
#define WAITV0() asm volatile("s_waitcnt vmcnt(0)" ::: "memory")
#define SBAR()   do { __builtin_amdgcn_s_barrier(); __builtin_amdgcn_sched_barrier(0); } while (0)

// ---------------------------------------------------------------- bucket ----
__global__ __launch_bounds__(256) void bucket_kernel(const int* cat32, int* perm,
                                                     int* off, int* cnt, int* dom) {
  __shared__ int scnt[NDOM], soff[NDOM], scur[NDOM];
  __shared__ int odd_nz;
  int t = threadIdx.x;
  if (t == 0) odd_nz = 0;
  if (t < NDOM) scnt[t] = 0;
  __syncthreads();
  int loc = 0;
  for (int i = t; i < B_; i += 256)
    if ((i & 1) && cat32[i] != 0) loc = 1;
  if (loc) atomicOr(&odd_nz, 1);
  __syncthreads();
  int strd = odd_nz ? 1 : 2;
  for (int i = t; i < B_; i += 256) atomicAdd(&scnt[cat32[i * strd]], 1);
  __syncthreads();
  if (t == 0) { int a = 0; for (int n = 0; n < NDOM; n++) { soff[n] = a; a += scnt[n]; } }
  __syncthreads();
  if (t < NDOM) { scur[t] = soff[t]; off[t] = soff[t]; cnt[t] = scnt[t]; }
  __syncthreads();
  for (int i = t; i < B_; i += 256) {
    int n = cat32[i * strd];
    int pos = atomicAdd(&scur[n], 1);
    perm[pos] = i;
    dom[pos] = n;
  }
}

// ---------------------------------------------------------------- cvt -------
__global__ __launch_bounds__(256) void cvt_kernel(const float* src, f16* dst, int n8) {
  int i = blockIdx.x * 256 + threadIdx.x;
  if (i >= n8) return;
  const f32x4* s = (const f32x4*)(src + (size_t)i * 8);
  f32x4 a = s[0], b = s[1];
  f16x8 o;
  o[0]=(f16)a[0]; o[1]=(f16)a[1]; o[2]=(f16)a[2]; o[3]=(f16)a[3];
  o[4]=(f16)b[0]; o[5]=(f16)b[1]; o[6]=(f16)b[2]; o[7]=(f16)b[3];
  *(f16x8*)(dst + (size_t)i * 8) = o;
}

// ------------------------------------------------------------ transpose -----
struct TRP { const float* s[10]; f16* wt; };

__global__ __launch_bounds__(256) void trans_kernel(TRP p) {
  const int m = blockIdx.z, z = m / 125, r = m % 125;
  const float* src; f16* dst; int R;
  const size_t zw = (size_t)z * ZWE;
  if (r < 54)       { src = p.s[0+z] + (size_t)r*E2;        dst = p.wt + zw + (size_t)r*E2;                 R = 768; }
  else if (r < 108) { int i=r-54;  src = p.s[2+z] + (size_t)i*E2;  dst = p.wt + zw + OFF_WT2 + (size_t)i*E2;  R = 768; }
  else if (r < 112) { int i=r-108; src = p.s[4+z] + (size_t)i*E2;  dst = p.wt + zw + OFF_SW1 + (size_t)i*E2;  R = 768; }
  else if (r < 116) { int i=r-112; src = p.s[6+z] + (size_t)i*E2;  dst = p.wt + zw + OFF_SW2 + (size_t)i*E2;  R = 768; }
  else              { int i=r-116; src = p.s[8+z] + (size_t)i*E2G; dst = p.wt + zw + OFF_GW1 + (size_t)i*E2G; R = 1536; }
  const int ty = blockIdx.y;
  if (ty * 64 >= R) return;
  const int tx = blockIdx.x;

  __shared__ f16 tile[64][76];   // 152B stride: write conflicts ~4-way (was 16-way)
  const int t = threadIdx.x;
  const int lr = t >> 4, lc = (t & 15) * 4;
#pragma unroll
  for (int i = 0; i < 4; i++) {
    int row = lr + i * 16;
    f32x4 v = *(const f32x4*)(src + (size_t)(ty*64 + row) * 768 + tx*64 + lc);
    tile[lc+0][row] = (f16)v[0];
    tile[lc+1][row] = (f16)v[1];
    tile[lc+2][row] = (f16)v[2];
    tile[lc+3][row] = (f16)v[3];
  }
  __syncthreads();
  const int orow = t >> 3, oc = (t & 7) * 8;
#pragma unroll
  for (int i = 0; i < 2; i++) {
    int r2 = orow + i * 32;
    union { f16x8 v8; f16x4 v4[2]; } u;
    u.v4[0] = *(const f16x4*)&tile[r2][oc];
    u.v4[1] = *(const f16x4*)&tile[r2][oc + 4];
    *(f16x8*)(dst + (size_t)(tx*64 + r2) * R + ty*64 + oc) = u.v8;
  }
}

// ---------------------------------------------------------------- layer 1 ---
struct L1P {
  const f16* x16[2]; const f16* demb16; const f16* wt;
  const float* b1[2]; const float* sb1[2]; const float* gb1[2];
  const int* perm; const int* off; const int* cnt;
  f16* h;
};

#define NBL1 3792   // 24 * 79 * 2
#define QX1  474    // NBL1 / 8

__global__ __launch_bounds__(256, 3) void layer1_kernel(L1P p) {
  const int raw = blockIdx.x;
  const int L = (raw & 7) * QX1 + (raw >> 3);   // bijective XCD chunking
  const int z = L / 1896;
  const int rem = L - z * 1896;
  const int g = rem / 24;
  const int x = rem % 24;
  const int nt = x % 6;
  int mt0 = x / 6, mtstep = 4;

  int row_off, row_cnt, slot, gdom = 0, kiters = KI1;
  const f16* WT; const float* bias;
  bool isGate = false;
  const size_t zw = (size_t)z * ZWE;
  if (g < 54) {
    int n = g / 6, e = g % 6;
    row_off = p.off[n]; row_cnt = p.cnt[n];
    WT = p.wt + zw + (size_t)(n*6+e) * E2;
    bias = p.b1[z] + (n*6+e) * D_;
    slot = e;
  } else if (g < 70) {
    int s_ = g - 54, e = s_ >> 2;
    row_off = 0; row_cnt = B_;
    WT = p.wt + zw + OFF_SW1 + (size_t)e * E2;
    bias = p.sb1[z] + e * D_;
    slot = 6 + e;
    mt0 = x / 6 + 4 * (s_ & 3); mtstep = 16;
  } else {
    int n = g - 70;
    row_off = p.off[n]; row_cnt = p.cnt[n];
    WT = p.wt + zw + OFF_GW1 + (size_t)n * E2G;
    bias = p.gb1[z] + n * D_;
    slot = 10; isGate = true; gdom = n; kiters = 2 * KI1;
  }
  const int KW = isGate ? 2 * D_ : D_;

  __shared__ f16 As[3][MT][KT];
  __shared__ f16 Bs[3][MT][KT];

  const int t = threadIdx.x;
  const int wave = t >> 6, lane = t & 63;
  const int wr = (wave >> 1) * 64, wc = (wave & 1) * 64;
  const int r0 = lane & 15, q = lane >> 4;
  const int jbase = nt * NT;
  const int lrow = lane >> 2;
  // pre-swizzled global source chunk: LDS[row][c] = global chunk c ^ ((row>>1)&3)
  const int lk = 8 * ((lane & 3) ^ ((lane >> 3) & 3));
  // frag-read swizzled chunk offset (row = ...16K + r0 -> s = (r0>>1)&3)
  const int qa = (q ^ ((r0 >> 1) & 3)) * 8;

  const f16* bBase[2];
#pragma unroll
  for (int i = 0; i < 2; i++) {
    int col = jbase + 32 * wave + 16 * i + lrow;
    bBase[i] = WT + (size_t)col * KW + lk;
  }
  const f16* dB = p.demb16 + (size_t)gdom * D_ + lk;

  for (int mt = mt0; mt * MT < row_cnt; mt += mtstep) {
    const f16* aBase[2];
#pragma unroll
    for (int i = 0; i < 2; i++) {
      int rl = mt * MT + 32 * wave + 16 * i + lrow;
      int pr = p.perm[(rl < row_cnt) ? (row_off + rl) : row_off];
      aBase[i] = p.x16[z] + (size_t)pr * D_ + lk;
    }

    auto STAGE = [&](int buf, int kk) {
      const int k0 = kk * KT;
#pragma unroll
      for (int i = 0; i < 2; i++) {
        const f16* as;
        if (isGate) as = (k0 < D_) ? (dB + k0) : (aBase[i] + (k0 - D_));
        else        as = aBase[i] + k0;
        gload16(as, &As[buf][32 * wave + 16 * i][0]);
        gload16(bBase[i] + k0, &Bs[buf][32 * wave + 16 * i][0]);
      }
    };

    f32x4 acc[4][4];
#pragma unroll
    for (int a = 0; a < 4; a++)
#pragma unroll
      for (int b = 0; b < 4; b++) acc[a][b] = (f32x4){0.f, 0.f, 0.f, 0.f};

    STAGE(0, 0);
    STAGE(1, 1);
    WAITV4();
    SBAR();

    int cur = 0;
    for (int kk = 0; kk < kiters; kk++) {
      int pf = cur + 2; if (pf >= 3) pf -= 3;
      if (kk + 2 < kiters) STAGE(pf, kk + 2);
      f16x8 af[4], bf[4];
#pragma unroll
      for (int m = 0; m < 4; m++) af[m] = *(const f16x8*)&As[cur][wr + m * 16 + r0][qa];
#pragma unroll
      for (int nn = 0; nn < 4; nn++) bf[nn] = *(const f16x8*)&Bs[cur][wc + nn * 16 + r0][qa];
      __builtin_amdgcn_s_setprio(1);
#pragma unroll
      for (int m = 0; m < 4; m++)
#pragma unroll
        for (int nn = 0; nn < 4; nn++)
          acc[m][nn] = __builtin_amdgcn_mfma_f32_16x16x32_f16(af[m], bf[nn], acc[m][nn], 0, 0, 0);
      __builtin_amdgcn_s_setprio(0);
      if (kk + 2 < kiters) { WAITV4(); } else { WAITV0(); }
      SBAR();
      cur = (cur == 2) ? 0 : cur + 1;
    }

    f16* hout = p.h + (size_t)(z * 11 + slot) * B_ * D_;
#pragma unroll
    for (int nn = 0; nn < 4; nn++) {
      const int col = jbase + wc + nn * 16 + r0;
      const float bc = bias[col];
#pragma unroll
      for (int m = 0; m < 4; m++) {
#pragma unroll
        for (int i = 0; i < 4; i++) {
          int lr = mt * MT + wr + m * 16 + q * 4 + i;
          if (lr < row_cnt) {
            float v = acc[m][nn][i] + bc;
            v = v / (1.f + __expf(-v));
            hout[(size_t)(row_off + lr) * D_ + col] = (f16)v;
          }
        }
      }
    }
  }
}

// ---------------------------------------------------------------- gate ------
struct GP {
  const f16* h;
  const float* gW2[2]; const float* gb2[2]; const float* temp[2];
  const int* dom;
  float* gates;
};

__global__ __launch_bounds__(256) void gate_kernel(GP p) {
  int wid = (blockIdx.x * 256 + threadIdx.x) >> 6;
  int lane = threadIdx.x & 63;
  int z = wid >> 11;
  int pos = wid & (B_ - 1);
  int n = p.dom[pos];
  const f16* gh = p.h + ((size_t)(z * 11 + 10) * B_ + pos) * D_;
  const float* W = p.gW2[z] + (size_t)n * D_ * NTOT;
  float part[NTOT];
#pragma unroll
  for (int e = 0; e < NTOT; e++) part[e] = 0.f;
  for (int k = lane; k < D_; k += 64) {
    float a = (float)gh[k];
    const float* wrow = W + (size_t)k * NTOT;
#pragma unroll
    for (int e = 0; e < NTOT; e++) part[e] = fmaf(a, wrow[e], part[e]);
  }
#pragma unroll
  for (int e = 0; e < NTOT; e++) {
    float v = part[e];
#pragma unroll
    for (int s = 32; s > 0; s >>= 1) v += __shfl_xor(v, s, 64);
    part[e] = v;
  }
  float tv = p.temp[z][n];
  float tq = (tv > 15.f ? tv : log1pf(__expf(tv))) + 1e-4f;
  const float* b2 = p.gb2[z] + n * NTOT;
  float mx = -1e30f;
#pragma unroll
  for (int e = 0; e < NTOT; e++) { part[e] = (part[e] + b2[e]) / tq; mx = fmaxf(mx, part[e]); }
  float s = 0.f;
#pragma unroll
  for (int e = 0; e < NTOT; e++) { part[e] = __expf(part[e] - mx); s += part[e]; }
  float inv = 1.f / s;
  if (lane < NTOT) p.gates[((size_t)z * B_ + pos) * NTOT + lane] = part[lane] * inv;
}

// ---------------------------------------------------------------- layer 2 ---
struct L2P {
  const f16* h; const f16* wt;
  const float* b2[2]; const float* sb2[2];
  const float* gates;
  const int* perm; const int* off; const int* cnt;
  float* out;
};

#define NBL2 2160   // 24 * 9 * 10
#define QX2  270    // NBL2 / 8

__global__ __launch_bounds__(256, 3) void layer2_kernel(L2P p) {
  const int raw = blockIdx.x;
  const int L = (raw & 7) * QX2 + (raw >> 3);
  const int zz = L / 216;
  const int rem = L % 216;
  const int n = rem / 24;
  const int x = rem % 24;
  const int z = zz / 5, es = zz % 5, ebase = es * 2;
  const int nt = x % 6, mt0 = x / 6;
  const int row_off = p.off[n], row_cnt = p.cnt[n];

  __shared__ f16 As[3][MT][KT];
  __shared__ f16 Bs[3][MT][KT];
  __shared__ float sg[MT][2];
  __shared__ int sperm[MT];

  const int t = threadIdx.x;
  const int wave = t >> 6, lane = t & 63;
  const int wr = (wave >> 1) * 64, wc = (wave & 1) * 64;
  const int r0 = lane & 15, q = lane >> 4;
  const int jbase = nt * NT;
  const int lrow = lane >> 2;
  const int lk = 8 * ((lane & 3) ^ ((lane >> 3) & 3));
  const int qa = (q ^ ((r0 >> 1) & 3)) * 8;

  const size_t zw = (size_t)z * ZWE;
  const f16* WB0; const f16* WB1; const float* pb[2]; size_t slotOff[2];
  {
    int e0 = ebase, e1 = ebase + 1;
    WB0 = (e0 < 6) ? (p.wt + zw + OFF_WT2 + (size_t)(n*6+e0)*E2) : (p.wt + zw + OFF_SW2 + (size_t)(e0-6)*E2);
    WB1 = (e1 < 6) ? (p.wt + zw + OFF_WT2 + (size_t)(n*6+e1)*E2) : (p.wt + zw + OFF_SW2 + (size_t)(e1-6)*E2);
    pb[0] = (e0 < 6) ? (p.b2[z] + (size_t)(n*6+e0)*D_) : (p.sb2[z] + (size_t)(e0-6)*D_);
    pb[1] = (e1 < 6) ? (p.b2[z] + (size_t)(n*6+e1)*D_) : (p.sb2[z] + (size_t)(e1-6)*D_);
    slotOff[0] = (size_t)(z*11 + e0) * B_ * D_;
    slotOff[1] = (size_t)(z*11 + e1) * B_ * D_;
  }

  const f16* bB0[2]; const f16* bB1[2];
#pragma unroll
  for (int i = 0; i < 2; i++) {
    int col = jbase + 32 * wave + 16 * i + lrow;
    bB0[i] = WB0 + (size_t)col * D_ + lk;
    bB1[i] = WB1 + (size_t)col * D_ + lk;
  }

  for (int mt = mt0; mt * MT < row_cnt; mt += 4) {
    for (int i = t; i < MT * 2; i += 256) {
      int rr = i >> 1, e = i & 1;
      int gp = row_off + mt * MT + rr;
      sg[rr][e] = (gp < B_ && (mt * MT + rr) < row_cnt)
                  ? p.gates[((size_t)z * B_ + gp) * NTOT + ebase + e] : 0.f;
    }
    for (int i = t; i < MT; i += 256) {
      int gp = row_off + mt * MT + i;
      sperm[i] = (gp < B_) ? p.perm[gp] : 0;
    }
    __syncthreads();

    const f16* aB0[2]; const f16* aB1[2];
#pragma unroll
    for (int i = 0; i < 2; i++) {
      int rl = mt * MT + 32 * wave + 16 * i + lrow;
      int rr = (rl < row_cnt) ? (row_off + rl) : row_off;
      size_t rp = (size_t)rr * D_ + lk;
      aB0[i] = p.h + slotOff[0] + rp;
      aB1[i] = p.h + slotOff[1] + rp;
    }
    f16 gA[4], gB[4];
#pragma unroll
    for (int m = 0; m < 4; m++) {
      gA[m] = (f16)sg[wr + m * 16 + r0][0];
      gB[m] = (f16)sg[wr + m * 16 + r0][1];
    }

    auto STAGE = [&](int buf, int it) {
      const int ei = (it >= KI1);
      const int k0 = (it - (ei ? KI1 : 0)) * KT;
#pragma unroll
      for (int i = 0; i < 2; i++) {
        const f16* as = (ei ? aB1[i] : aB0[i]) + k0;
        const f16* bs = (ei ? bB1[i] : bB0[i]) + k0;
        gload16(as, &As[buf][32 * wave + 16 * i][0]);
        gload16(bs, &Bs[buf][32 * wave + 16 * i][0]);
      }
    };

    f32x4 acc[4][4];
#pragma unroll
    for (int a = 0; a < 4; a++)
#pragma unroll
      for (int b = 0; b < 4; b++) acc[a][b] = (f32x4){0.f, 0.f, 0.f, 0.f};

    const int total = 2 * KI1;   // 48
    STAGE(0, 0);
    STAGE(1, 1);
    WAITV4();
    SBAR();

    int cur = 0;
    for (int it = 0; it < total; it++) {
      int pf = cur + 2; if (pf >= 3) pf -= 3;
      if (it + 2 < total) STAGE(pf, it + 2);
      const int ei = (it >= KI1);
      f16x8 af[4], bf[4];
#pragma unroll
      for (int m = 0; m < 4; m++) {
        af[m] = *(const f16x8*)&As[cur][wr + m * 16 + r0][qa];
        af[m] = af[m] * (ei ? gB[m] : gA[m]);
      }
#pragma unroll
      for (int nn = 0; nn < 4; nn++) bf[nn] = *(const f16x8*)&Bs[cur][wc + nn * 16 + r0][qa];
      __builtin_amdgcn_s_setprio(1);
#pragma unroll
      for (int m = 0; m < 4; m++)
#pragma unroll
        for (int nn = 0; nn < 4; nn++)
          acc[m][nn] = __builtin_amdgcn_mfma_f32_16x16x32_f16(af[m], bf[nn], acc[m][nn], 0, 0, 0);
      __builtin_amdgcn_s_setprio(0);
      if (it + 2 < total) { WAITV4(); } else { WAITV0(); }
      SBAR();
      cur = (cur == 2) ? 0 : cur + 1;
    }

    const int zoff = z * D_;
#pragma unroll
    for (int nn = 0; nn < 4; nn++) {
      const int col = jbase + wc + nn * 16 + r0;
      float pbc0 = pb[0][col], pbc1 = pb[1][col];
#pragma unroll
      for (int m = 0; m < 4; m++) {
#pragma unroll
        for (int i = 0; i < 4; i++) {
          const int lrt = wr + m * 16 + q * 4 + i;
          if (mt * MT + lrt < row_cnt) {
            float v = acc[m][nn][i];
            v = fmaf(sg[lrt][0], pbc0, v);
            v = fmaf(sg[lrt][1], pbc1, v);
            float* dst = p.out + (size_t)sperm[lrt] * (2 * D_) + zoff + col;
            __hip_atomic_fetch_add(dst, v, __ATOMIC_RELAXED, __HIP_MEMORY_SCOPE_AGENT);
          }
        }
      }
    }
    __syncthreads();
  }
}

// ---------------------------------------------------------------- launch ----
extern "C" void kernel_launch(void* const* d_in, const int* in_sizes, int n_in,
                              void* d_out, int out_size, void* d_ws, size_t ws_size,
                              hipStream_t stream) {
  const float* content = (const float*)d_in[0];
  const float* ftr     = (const float*)d_in[1];
  const int*   cat     = (const int*)d_in[2];
  const float* demb    = (const float*)d_in[3];

  const float* cW1  = (const float*)d_in[4];
  const float* cb1  = (const float*)d_in[5];
  const float* cW2  = (const float*)d_in[6];
  const float* cb2  = (const float*)d_in[7];
  const float* csW1 = (const float*)d_in[8];
  const float* csb1 = (const float*)d_in[9];
  const float* csW2 = (const float*)d_in[10];
  const float* csb2 = (const float*)d_in[11];
  const float* cgW1 = (const float*)d_in[12];
  const float* cgb1 = (const float*)d_in[13];
  const float* cgW2 = (const float*)d_in[14];
  const float* cgb2 = (const float*)d_in[15];
  const float* ctemp= (const float*)d_in[16];

  const float* fW1  = (const float*)d_in[17];
  const float* fb1  = (const float*)d_in[18];
  const float* fW2  = (const float*)d_in[19];
  const float* fb2  = (const float*)d_in[20];
  const float* fsW1 = (const float*)d_in[21];
  const float* fsb1 = (const float*)d_in[22];
  const float* fsW2 = (const float*)d_in[23];
  const float* fsb2 = (const float*)d_in[24];
  const float* fgW1 = (const float*)d_in[25];
  const float* fgb1 = (const float*)d_in[26];
  const float* fgW2 = (const float*)d_in[27];
  const float* fgb2 = (const float*)d_in[28];
  const float* ftemp= (const float*)d_in[29];

  char* wsb = (char*)d_ws;
  int* perm    = (int*)wsb;                        // 8 KB
  int* off     = (int*)(wsb + 8192);
  int* cnt     = (int*)(wsb + 8256);
  int* dom     = (int*)(wsb + 8320);               // 8 KB
  float* gates = (float*)(wsb + 16512);            // 160 KB
  f16* h       = (f16*)(wsb + 180352);             // 66 MB
  f16* x16a    = (f16*)(wsb + 69386368);           // 3 MB
  f16* x16b    = (f16*)(wsb + 72532096);           // 3 MB
  f16* demb16  = (f16*)(wsb + 75677824);           // 13.5 KB
  f16* wt      = (f16*)(wsb + 75691648);           // 316 MB
  float* out   = (float*)d_out;

  (void)hipMemsetAsync(d_out, 0, (size_t)out_size * sizeof(float), stream);

  bucket_kernel<<<1, 256, 0, stream>>>(cat, perm, off, cnt, dom);

  cvt_kernel<<<768, 256, 0, stream>>>(content, x16a, (B_ * D_) / 8);
  cvt_kernel<<<768, 256, 0, stream>>>(ftr, x16b, (B_ * D_) / 8);
  cvt_kernel<<<4, 256, 0, stream>>>(demb, demb16, (NDOM * D_) / 8);

  TRP tp;
  tp.s[0] = cW1;  tp.s[1] = fW1;
  tp.s[2] = cW2;  tp.s[3] = fW2;
  tp.s[4] = csW1; tp.s[5] = fsW1;
  tp.s[6] = csW2; tp.s[7] = fsW2;
  tp.s[8] = cgW1; tp.s[9] = fgW1;
  tp.wt = wt;
  trans_kernel<<<dim3(12, 24, 250), 256, 0, stream>>>(tp);

  L1P p1;
  p1.x16[0] = x16a; p1.x16[1] = x16b; p1.demb16 = demb16; p1.wt = wt;
  p1.b1[0] = cb1;  p1.b1[1] = fb1;
  p1.sb1[0] = csb1; p1.sb1[1] = fsb1;
  p1.gb1[0] = cgb1; p1.gb1[1] = fgb1;
  p1.perm = perm; p1.off = off; p1.cnt = cnt; p1.h = h;
  layer1_kernel<<<dim3(NBL1), 256, 0, stream>>>(p1);

  GP pg;
  pg.h = h; pg.gW2[0] = cgW2; pg.gW2[1] = fgW2;
  pg.gb2[0] = cgb2; pg.gb2[1] = fgb2;
  pg.temp[0] = ctemp; pg.temp[1] = ftemp;
  pg.dom = dom; pg.gates = gates;
  gate_kernel<<<dim3((2 * B_) / 4), 256, 0, stream>>>(pg);

  L2P p2;
  p2.h = h; p2.wt = wt;
  p2.b2[0] = cb2;  p2.b2[1] = fb2;
  p2.sb2[0] = csb2; p2.sb2[1] = fsb2;
  p2.gates = gates; p2.perm = perm; p2.off = off; p2.cnt = cnt; p2.out = out;
  layer2_kernel<<<dim3(NBL2), 256, 0, stream>>>(p2);

  (void)in_sizes; (void)n_in; (void)ws_size;
}